// Round 3
// baseline (111.023 us; speedup 1.0000x reference)
//
#include <hip/hip_runtime.h>
#include <stdint.h>

#define NB   8
#define SEQ  2048
#define DIM  128
#define NELEM (NB * SEQ * DIM)        /* 2,097,152 */
#define SHIFT 40.0f

typedef __attribute__((ext_vector_type(8))) short    short8;
typedef __attribute__((ext_vector_type(4))) float    f32x4;
typedef __attribute__((ext_vector_type(8))) _Float16 half8;
typedef __attribute__((ext_vector_type(4))) _Float16 half4;

__device__ __forceinline__ unsigned short f2bf(float f) {
  unsigned int u = __float_as_uint(f);
  u += 0x7fffu + ((u >> 16) & 1u);          // round-to-nearest-even
  return (unsigned short)(u >> 16);
}
__device__ __forceinline__ float bf2f(unsigned int h) {
  return __uint_as_float(h << 16);
}

// ---------------- prologue 1: Q,K fp32 -> fp16 planes ----------------
extern "C" __global__ __launch_bounds__(256)
void prep_qk(const float* __restrict__ Q, const float* __restrict__ K,
             _Float16* __restrict__ Qf, _Float16* __restrict__ Kf) {
  const int n4 = NELEM / 4;
  for (int i = blockIdx.x * 256 + threadIdx.x; i < n4; i += gridDim.x * 256) {
    float4 q = ((const float4*)Q)[i];
    float4 k = ((const float4*)K)[i];
    half4 qo = { (_Float16)q.x, (_Float16)q.y, (_Float16)q.z, (_Float16)q.w };
    half4 ko = { (_Float16)k.x, (_Float16)k.y, (_Float16)k.z, (_Float16)k.w };
    *(half4*)(Qf + 4 * (size_t)i) = qo;
    *(half4*)(Kf + 4 * (size_t)i) = ko;
  }
}

// ---------------- prologue 2: V fp32 -> bf16 transposed Vt[b][d][k] ----------------
extern "C" __global__ __launch_bounds__(256)
void prep_v(const float* __restrict__ V, unsigned short* __restrict__ Vt) {
  __shared__ float tile[64][65];
  const int bid = blockIdx.x;
  const int b = bid & 7;
  const int rest = bid >> 3;
  const int d0 = (rest & 1) << 6;
  const int k0 = (rest >> 1) << 6;
  const float* Vb = V + (size_t)b * SEQ * DIM;
  unsigned short* Vtb = Vt + (size_t)b * DIM * SEQ;
  const int tx = threadIdx.x & 63, ty = threadIdx.x >> 6;
#pragma unroll
  for (int r = 0; r < 16; ++r) {
    int k = (r << 2) + ty;
    tile[k][tx] = Vb[(size_t)(k0 + k) * DIM + d0 + tx];
  }
  __syncthreads();
#pragma unroll
  for (int r = 0; r < 16; ++r) {
    int d = (r << 2) + ty;
    Vtb[(size_t)(d0 + d) * SEQ + k0 + tx] = f2bf(tile[tx][d]);
  }
}

// ---------------- main fused kernel ----------------
// One block = one (batch, 32-query-row) tile, 1024 threads = 16 waves.
// amdgpu_waves_per_eu(4,4): LDS (147 KiB) caps us at 1 block/CU = 4 waves/SIMD;
// telling the scheduler max=4 stops the 64-VGPR occupancy squeeze so the
// register-resident K/V prefetch pipelines actually materialize (target ~128 VGPR).
// Phase A: wave w owns k in [128w,128w+128): S = Q K^T (fp16 MFMA), e=exp(S-40)
//          -> LDS bf16 (swizzled), row sums.  3-deep K prefetch.
// Phase B: wave w = (d-tile w&7, k-half w>>3); PV partials merged via LDS.
// Epilogue: O write (waves 0-7) + dedicated coalesced W pass (all waves).
extern "C" __global__ __launch_bounds__(1024)
__attribute__((amdgpu_waves_per_eu(4, 4)))
void sdpa_main(const _Float16* __restrict__ Qf, const _Float16* __restrict__ Kf,
               const unsigned short* __restrict__ Vt, float* __restrict__ Og) {
  extern __shared__ char lds[];
  char*  e_lds = lds;                               // [32][4096 B] bf16, byte ^= (q&7)<<4
  float* red   = (float*)(lds + 131072);            // [16][32]
  float* linv  = (float*)(lds + 131072 + 2048);     // [32]
  float* pred  = (float*)(lds + 131072 + 2048 + 128); // [8][2][64] f32x4 partials (16 KiB)

  const int tid = threadIdx.x;
  const int w   = tid >> 6;                         // 0..15
  const int l   = tid & 63;
  const int l15 = l & 15;
  const int lk  = l >> 4;

  const int b  = blockIdx.x & 7;                    // batch -> XCD affinity
  const int q0 = (blockIdx.x >> 3) << 5;

  const _Float16* Qb = Qf + ((size_t)b * SEQ + q0) * DIM;
  const _Float16* Kb = Kf + (size_t)b * SEQ * DIM;
  const unsigned short* Vtb = Vt + (size_t)b * DIM * SEQ;
  float* Oo = Og + ((size_t)b * SEQ + q0) * DIM;
  float* Wo = Og + (size_t)NB * SEQ * DIM + ((size_t)b * SEQ + q0) * SEQ;

  // Q fragments (A operand: m = l&15, k = lk*8 + j), direct half8 loads
  half8 qf[2][4];
#pragma unroll
  for (int g = 0; g < 2; ++g) {
    const _Float16* qrow = Qb + (size_t)(16 * g + l15) * DIM + lk * 8;
#pragma unroll
    for (int t = 0; t < 4; ++t) qf[g][t] = *(const half8*)(qrow + 32 * t);
  }

  float ps[2][4] = {{0.f,0.f,0.f,0.f},{0.f,0.f,0.f,0.f}};
  half8 kA[4], kB[4], kC[4];

#define KLOAD(KF, sub) do {                                                       \
  const _Float16* kr_ = Kb + (size_t)(((w << 7) + ((sub) << 4)) + l15) * DIM + lk * 8; \
  _Pragma("unroll") for (int t = 0; t < 4; ++t) KF[t] = *(const half8*)(kr_ + 32 * t); \
} while (0)

#define ACOMP(KF, sub) do {                                                       \
  const int kb_ = (w << 7) + ((sub) << 4);                                        \
  _Pragma("unroll") for (int g = 0; g < 2; ++g) {                                 \
    f32x4 acc = {0.f, 0.f, 0.f, 0.f};                                             \
    _Pragma("unroll") for (int t = 0; t < 4; ++t)                                 \
      acc = __builtin_amdgcn_mfma_f32_16x16x32_f16(qf[g][t], KF[t], acc, 0, 0, 0);\
    _Pragma("unroll") for (int r = 0; r < 4; ++r) {                               \
      float e_ = __expf(acc[r] - SHIFT);                                          \
      ps[g][r] += e_;                                                             \
      int q_  = 16 * g + lk * 4 + r;                                              \
      int byt = (q_ << 12) + ((kb_ + l15) << 1); byt ^= (q_ & 7) << 4;            \
      *(unsigned short*)(e_lds + byt) = f2bf(e_);                                 \
    } }                                                                           \
} while (0)

  // Phase A: 8 k-subtiles per wave, 3-deep prefetch (distance-2 load cover)
  KLOAD(kA, 0); KLOAD(kB, 1);
  KLOAD(kC, 2); ACOMP(kA, 0);
  KLOAD(kA, 3); ACOMP(kB, 1);
  KLOAD(kB, 4); ACOMP(kC, 2);
  KLOAD(kC, 5); ACOMP(kA, 3);
  KLOAD(kA, 6); ACOMP(kB, 4);
  KLOAD(kB, 7); ACOMP(kC, 5);
  ACOMP(kA, 6); ACOMP(kB, 7);
#undef KLOAD
#undef ACOMP

  // row-sum reduce (16 lanes share a q-row) + 16-wave combine
#pragma unroll
  for (int g = 0; g < 2; ++g)
#pragma unroll
    for (int r = 0; r < 4; ++r) {
      float v = ps[g][r];
      v += __shfl_xor(v, 1);
      v += __shfl_xor(v, 2);
      v += __shfl_xor(v, 4);
      v += __shfl_xor(v, 8);
      if (l15 == 0) red[w * 32 + 16 * g + lk * 4 + r] = v;
    }
  __syncthreads();
  if (tid < 32) {
    float s = 0.f;
#pragma unroll
    for (int i = 0; i < 16; ++i) s += red[i * 32 + tid];
    linv[tid] = 1.0f / s;
  }
  __syncthreads();

  // Phase B: wave w -> d-tile (w&7), k-half (w>>3); 32 PV steps of 32 k each
  const int d0   = (w & 7) << 4;
  const int base = (w >> 3) << 5;                   // 0 or 32
  const size_t vbase = (size_t)(d0 + l15) * SEQ + lk * 8;
  f32x4 acc2[2] = {{0.f,0.f,0.f,0.f},{0.f,0.f,0.f,0.f}};
  short8 vA, vB, vC;

#define VLOAD(buf, stp) do { buf = *(const short8*)(Vtb + vbase + ((size_t)(stp) << 5)); } while (0)

#define VUSE(buf, stp) do {                                                      \
  int _kb2 = ((((stp) << 5) + lk * 8) << 1);                                     \
  _Pragma("unroll") for (int g = 0; g < 2; ++g) {                                \
    int _q  = 16 * g + l15;                                                      \
    int _by = (_q << 12) + _kb2; _by ^= (_q & 7) << 4;                           \
    short8 _af = *(const short8*)(e_lds + _by);                                  \
    acc2[g] = __builtin_amdgcn_mfma_f32_16x16x32_bf16(_af, buf, acc2[g], 0, 0, 0); \
  }                                                                              \
} while (0)

  VLOAD(vA, base + 0); VLOAD(vB, base + 1);
#pragma unroll
  for (int i = 0; i < 10; ++i) {
    const int s0 = base + 3 * i;
    VLOAD(vC, s0 + 2);
    VUSE(vA, s0);
    if (3 * i + 3 < 32) VLOAD(vA, s0 + 3);
    VUSE(vB, s0 + 1);
    if (3 * i + 4 < 32) VLOAD(vB, s0 + 4);
    VUSE(vC, s0 + 2);
  }
  VUSE(vA, base + 30);
  VUSE(vB, base + 31);
#undef VLOAD
#undef VUSE

  // merge k-half partials: waves 8-15 export, waves 0-7 import+add
  if (w >= 8) {
#pragma unroll
    for (int g = 0; g < 2; ++g)
      *(f32x4*)(pred + (((size_t)(w - 8) * 2 + g) * 64 + l) * 4) = acc2[g];
  }
  __syncthreads();
  if (w < 8) {
#pragma unroll
    for (int g = 0; g < 2; ++g) {
      f32x4 p = *(const f32x4*)(pred + (((size_t)w * 2 + g) * 64 + l) * 4);
      acc2[g] += p;
    }
    // O write
#pragma unroll
    for (int g = 0; g < 2; ++g)
#pragma unroll
      for (int r = 0; r < 4; ++r) {
        int q = 16 * g + lk * 4 + r;
        Oo[(size_t)q * DIM + d0 + l15] = acc2[g][r] * linv[q];
      }
  }

  // W pass: 32 rows x 512 float4, 16 per thread, coalesced
#pragma unroll
  for (int i = 0; i < 16; ++i) {
    int idx = (i << 10) + tid;             // 0..16383
    int row = idx >> 9;
    int c4  = idx & 511;
    float sc = linv[row];
    int byt = (row << 12) + (c4 << 3); byt ^= (row & 7) << 4;
    uint2 e4 = *(const uint2*)(e_lds + byt);
    float4 o;
    o.x = bf2f(e4.x & 0xffffu) * sc; o.y = bf2f(e4.x >> 16) * sc;
    o.z = bf2f(e4.y & 0xffffu) * sc; o.w = bf2f(e4.y >> 16) * sc;
    *(float4*)(Wo + (size_t)row * SEQ + (c4 << 2)) = o;
  }
}

// ---------------- fallback (round-1 kernel, no workspace needed) ----------------
extern "C" __global__ __launch_bounds__(512, 2)
void sdpa_fused(const float* __restrict__ Qg, const float* __restrict__ Kg,
                const float* __restrict__ Vg, float* __restrict__ Og) {
  extern __shared__ char lds[];
  char*  e_lds = lds;
  float* red   = (float*)(lds + 131072);
  float* linv  = (float*)(lds + 131072 + 1024);

  const int tid = threadIdx.x;
  const int w   = tid >> 6;
  const int l   = tid & 63;
  const int l15 = l & 15;
  const int lk  = l >> 4;

  const int b  = blockIdx.x & 7;
  const int q0 = (blockIdx.x >> 3) << 5;

  const float* Qb = Qg + ((size_t)b * SEQ + q0) * DIM;
  const float* Kb = Kg + (size_t)b * SEQ * DIM;
  const float* Vb = Vg + (size_t)b * SEQ * DIM;
  float* Oo = Og + ((size_t)b * SEQ + q0) * DIM;
  float* Wo = Og + (size_t)NB * SEQ * DIM + ((size_t)b * SEQ + q0) * SEQ;

  short8 qh[2][4], ql[2][4];
#pragma unroll
  for (int g = 0; g < 2; ++g) {
    const float* qrow = Qb + (16 * g + l15) * DIM + lk * 8;
#pragma unroll
    for (int t = 0; t < 4; ++t) {
      float4 a = *(const float4*)(qrow + 32 * t);
      float4 c = *(const float4*)(qrow + 32 * t + 4);
      float vv[8] = {a.x, a.y, a.z, a.w, c.x, c.y, c.z, c.w};
      short8 h, lo;
#pragma unroll
      for (int j = 0; j < 8; ++j) {
        unsigned short hb = f2bf(vv[j]);
        h[j]  = (short)hb;
        lo[j] = (short)f2bf(vv[j] - bf2f(hb));
      }
      qh[g][t] = h; ql[g][t] = lo;
    }
  }

  float ps[2][4] = {{0.f,0.f,0.f,0.f},{0.f,0.f,0.f,0.f}};
  for (int sub = 0; sub < 16; ++sub) {
    const int kb = (w << 8) + (sub << 4);
    const float* krow = Kb + (kb + l15) * DIM + lk * 8;
    short8 kh[4], kl[4];
#pragma unroll
    for (int t = 0; t < 4; ++t) {
      float4 a = *(const float4*)(krow + 32 * t);
      float4 c = *(const float4*)(krow + 32 * t + 4);
      float vv[8] = {a.x, a.y, a.z, a.w, c.x, c.y, c.z, c.w};
      short8 h, lo;
#pragma unroll
      for (int j = 0; j < 8; ++j) {
        unsigned short hb = f2bf(vv[j]);
        h[j]  = (short)hb;
        lo[j] = (short)f2bf(vv[j] - bf2f(hb));
      }
      kh[t] = h; kl[t] = lo;
    }
#pragma unroll
    for (int g = 0; g < 2; ++g) {
      f32x4 acc = {0.f, 0.f, 0.f, 0.f};
#pragma unroll
      for (int t = 0; t < 4; ++t) {
        acc = __builtin_amdgcn_mfma_f32_16x16x32_bf16(qh[g][t], kh[t], acc, 0, 0, 0);
        acc = __builtin_amdgcn_mfma_f32_16x16x32_bf16(ql[g][t], kh[t], acc, 0, 0, 0);
        acc = __builtin_amdgcn_mfma_f32_16x16x32_bf16(qh[g][t], kl[t], acc, 0, 0, 0);
      }
#pragma unroll
      for (int r = 0; r < 4; ++r) {
        float e = __expf(acc[r] - SHIFT);
        ps[g][r] += e;
        int q   = 16 * g + lk * 4 + r;
        int byt = (q << 12) + ((kb + l15) << 1);
        byt ^= (q & 7) << 4;
        *(unsigned short*)(e_lds + byt) = f2bf(e);
      }
    }
  }

#pragma unroll
  for (int g = 0; g < 2; ++g)
#pragma unroll
    for (int r = 0; r < 4; ++r) {
      float v = ps[g][r];
      v += __shfl_xor(v, 1);
      v += __shfl_xor(v, 2);
      v += __shfl_xor(v, 4);
      v += __shfl_xor(v, 8);
      if (l15 == 0) red[w * 32 + 16 * g + lk * 4 + r] = v;
    }
  __syncthreads();
  if (tid < 32) {
    float s = 0.f;
#pragma unroll
    for (int i = 0; i < 8; ++i) s += red[i * 32 + tid];
    linv[tid] = 1.0f / s;
  }
  __syncthreads();

  const int d0 = w << 4;
  const int vbase = lk * 8 * DIM + d0 + l15;
  f32x4 acc2[2] = {{0.f,0.f,0.f,0.f},{0.f,0.f,0.f,0.f}};
  float vA[8], vB[8], vC[8];

#define VLOAD(buf, stp) do { int _ko = (stp) * (32 * DIM) + vbase;               \
  _Pragma("unroll") for (int j = 0; j < 8; ++j) buf[j] = Vb[_ko + j * DIM]; } while (0)

#define VUSE(buf, stp) do {                                                      \
  short8 _bf; _Pragma("unroll") for (int j = 0; j < 8; ++j) _bf[j] = (short)f2bf(buf[j]); \
  int _kb2 = ((((stp) << 5) + lk * 8) << 1);                                     \
  _Pragma("unroll") for (int g = 0; g < 2; ++g) {                                \
    int _q  = 16 * g + l15;                                                      \
    int _by = (_q << 12) + _kb2; _by ^= (_q & 7) << 4;                           \
    short8 _af = *(const short8*)(e_lds + _by);                                  \
    acc2[g] = __builtin_amdgcn_mfma_f32_16x16x32_bf16(_af, _bf, acc2[g], 0, 0, 0); \
  }                                                                              \
  if (((stp) & 1) == 0) {                                                        \
    int _r = (stp) >> 1; float _sc = linv[_r];                                   \
    int _b2 = (_r << 12) + (tid << 3); _b2 ^= (_r & 7) << 4;                     \
    uint2 _e4 = *(const uint2*)(e_lds + _b2);                                    \
    float4 _o; _o.x = bf2f(_e4.x & 0xffffu) * _sc; _o.y = bf2f(_e4.x >> 16) * _sc; \
    _o.z = bf2f(_e4.y & 0xffffu) * _sc; _o.w = bf2f(_e4.y >> 16) * _sc;          \
    *(float4*)(Wo + (size_t)_r * SEQ + (tid << 2)) = _o;                         \
  }                                                                              \
} while (0)

  VLOAD(vA, 0); VLOAD(vB, 1);
  for (int i = 0; i < 21; ++i) {
    const int s0 = 3 * i;
    VLOAD(vC, s0 + 2);
    VUSE(vA, s0);
    if (s0 + 3 < 64) VLOAD(vA, s0 + 3);
    VUSE(vB, s0 + 1);
    if (s0 + 4 < 64) VLOAD(vB, s0 + 4);
    VUSE(vC, s0 + 2);
  }
  VUSE(vA, 63);
#undef VLOAD
#undef VUSE

#pragma unroll
  for (int g = 0; g < 2; ++g)
#pragma unroll
    for (int r = 0; r < 4; ++r) {
      int q = 16 * g + lk * 4 + r;
      Oo[(size_t)q * DIM + d0 + l15] = acc2[g][r] * linv[q];
    }
}

extern "C" void kernel_launch(void* const* d_in, const int* in_sizes, int n_in,
                              void* d_out, int out_size, void* d_ws, size_t ws_size,
                              hipStream_t stream) {
  const float* Q = (const float*)d_in[0];
  const float* K = (const float*)d_in[1];
  const float* V = (const float*)d_in[2];
  float* out = (float*)d_out;
  (void)in_sizes; (void)n_in; (void)out_size;

  const size_t need = (size_t)NELEM * 2u * 3u;   // Qf + Kf + Vt = 12,582,912 B
  if (ws_size >= need && d_ws != nullptr) {
    _Float16* Qf = (_Float16*)d_ws;
    _Float16* Kf = Qf + NELEM;
    unsigned short* Vt = (unsigned short*)(Kf + NELEM);
    prep_qk<<<dim3(2048), dim3(256), 0, stream>>>(Q, K, Qf, Kf);
    prep_v<<<dim3(512), dim3(256), 0, stream>>>(V, Vt);
    hipFuncSetAttribute((const void*)sdpa_main,
                        hipFuncAttributeMaxDynamicSharedMemorySize, 149632);
    sdpa_main<<<dim3(NB * (SEQ / 32)), dim3(1024), 149632, stream>>>(Qf, Kf, Vt, out);
  } else {
    hipFuncSetAttribute((const void*)sdpa_fused,
                        hipFuncAttributeMaxDynamicSharedMemorySize, 132224);
    sdpa_fused<<<dim3(NB * (SEQ / 32)), dim3(512), 132224, stream>>>(Q, K, V, out);
  }
}

// Round 4
// 85.632 us; speedup vs baseline: 1.2965x; 1.2965x over previous
//
#include <hip/hip_runtime.h>
#include <stdint.h>

#define NB   8
#define SEQ  2048
#define DIM  128
#define NELEM (NB * SEQ * DIM)        /* 2,097,152 */
#define SHIFT 40.0f

typedef __attribute__((ext_vector_type(8))) short    short8;
typedef __attribute__((ext_vector_type(4))) float    f32x4;
typedef __attribute__((ext_vector_type(8))) _Float16 half8;
typedef __attribute__((ext_vector_type(4))) _Float16 half4;

__device__ __forceinline__ unsigned short f2bf(float f) {
  unsigned int u = __float_as_uint(f);
  u += 0x7fffu + ((u >> 16) & 1u);          // round-to-nearest-even
  return (unsigned short)(u >> 16);
}
__device__ __forceinline__ float bf2f(unsigned int h) {
  return __uint_as_float(h << 16);
}

// ---------------- prologue 1: Q,K fp32 -> fp16 planes ----------------
extern "C" __global__ __launch_bounds__(256)
void prep_qk(const float* __restrict__ Q, const float* __restrict__ K,
             _Float16* __restrict__ Qf, _Float16* __restrict__ Kf) {
  const int n4 = NELEM / 4;
  for (int i = blockIdx.x * 256 + threadIdx.x; i < n4; i += gridDim.x * 256) {
    float4 q = ((const float4*)Q)[i];
    float4 k = ((const float4*)K)[i];
    half4 qo = { (_Float16)q.x, (_Float16)q.y, (_Float16)q.z, (_Float16)q.w };
    half4 ko = { (_Float16)k.x, (_Float16)k.y, (_Float16)k.z, (_Float16)k.w };
    *(half4*)(Qf + 4 * (size_t)i) = qo;
    *(half4*)(Kf + 4 * (size_t)i) = ko;
  }
}

// ---------------- prologue 2: V fp32 -> bf16 transposed Vt[b][d][k] ----------------
extern "C" __global__ __launch_bounds__(256)
void prep_v(const float* __restrict__ V, unsigned short* __restrict__ Vt) {
  __shared__ float tile[64][65];
  const int bid = blockIdx.x;
  const int b = bid & 7;
  const int rest = bid >> 3;
  const int d0 = (rest & 1) << 6;
  const int k0 = (rest >> 1) << 6;
  const float* Vb = V + (size_t)b * SEQ * DIM;
  unsigned short* Vtb = Vt + (size_t)b * DIM * SEQ;
  const int tx = threadIdx.x & 63, ty = threadIdx.x >> 6;
#pragma unroll
  for (int r = 0; r < 16; ++r) {
    int k = (r << 2) + ty;
    tile[k][tx] = Vb[(size_t)(k0 + k) * DIM + d0 + tx];
  }
  __syncthreads();
#pragma unroll
  for (int r = 0; r < 16; ++r) {
    int d = (r << 2) + ty;
    Vtb[(size_t)(d0 + d) * SEQ + k0 + tx] = f2bf(tile[tx][d]);
  }
}

// ---------------- main fused kernel ----------------
// Round-0 structure (512 threads = 8 waves, 32-q-row tile, 128 KiB e_lds,
// 1 block/CU => 2 waves/SIMD, LDS-capped). Occupancy cannot exceed 2 waves/SIMD
// regardless of VGPR count, so registers up to 256 are FREE: spend them on
// deeper prefetch pipelines to cover L2 latency with ILP.
//   amdgpu_waves_per_eu(2,2): min=2 -> allocator cap 256 VGPR; max=2 -> the
//   scheduler stops squeezing registers to chase impossible occupancy.
// Phase A: S = Q K^T (fp16 MFMA), e=exp(S-40) -> LDS bf16 (swizzled), row sums.
//          4-deep K prefetch (was 2).
// Phase B: O = (e @ V)/l via bf16 MFMA; 6-deep V prefetch (was 3);
//          W rows streamed interleaved.
extern "C" __global__ __launch_bounds__(512)
__attribute__((amdgpu_waves_per_eu(2, 2)))
void sdpa_main(const _Float16* __restrict__ Qf, const _Float16* __restrict__ Kf,
               const unsigned short* __restrict__ Vt, float* __restrict__ Og) {
  extern __shared__ char lds[];
  char*  e_lds = lds;                             // [32][4096 B] bf16, byte ^= (q&7)<<4
  float* red   = (float*)(lds + 131072);          // [8][32]
  float* linv  = (float*)(lds + 131072 + 1024);   // [32]

  const int tid = threadIdx.x;
  const int w   = tid >> 6;
  const int l   = tid & 63;
  const int l15 = l & 15;
  const int lk  = l >> 4;

  const int b  = blockIdx.x & 7;                  // batch -> XCD affinity
  const int q0 = (blockIdx.x >> 3) << 5;

  const _Float16* Qb = Qf + ((size_t)b * SEQ + q0) * DIM;
  const _Float16* Kb = Kf + (size_t)b * SEQ * DIM;
  const unsigned short* Vtb = Vt + (size_t)b * DIM * SEQ;
  float* Oo = Og + ((size_t)b * SEQ + q0) * DIM;
  float* Wo = Og + (size_t)NB * SEQ * DIM + ((size_t)b * SEQ + q0) * SEQ;

  // Q fragments (A operand: m = l&15, k = lk*8 + j), direct half8 loads
  half8 qf[2][4];
#pragma unroll
  for (int g = 0; g < 2; ++g) {
    const _Float16* qrow = Qb + (size_t)(16 * g + l15) * DIM + lk * 8;
#pragma unroll
    for (int t = 0; t < 4; ++t) qf[g][t] = *(const half8*)(qrow + 32 * t);
  }

  float ps[2][4] = {{0.f,0.f,0.f,0.f},{0.f,0.f,0.f,0.f}};
  half8 kA[4], kB[4], kC[4], kD[4];

#define KLOAD(KF, sub) do {                                                       \
  const _Float16* kr_ = Kb + (size_t)(((w << 8) + ((sub) << 4)) + l15) * DIM + lk * 8; \
  _Pragma("unroll") for (int t = 0; t < 4; ++t) KF[t] = *(const half8*)(kr_ + 32 * t); \
} while (0)

#define ACOMP(KF, sub) do {                                                       \
  const int kb_ = (w << 8) + ((sub) << 4);                                        \
  _Pragma("unroll") for (int g = 0; g < 2; ++g) {                                 \
    f32x4 acc = {0.f, 0.f, 0.f, 0.f};                                             \
    _Pragma("unroll") for (int t = 0; t < 4; ++t)                                 \
      acc = __builtin_amdgcn_mfma_f32_16x16x32_f16(qf[g][t], KF[t], acc, 0, 0, 0);\
    _Pragma("unroll") for (int r = 0; r < 4; ++r) {                               \
      float e_ = __expf(acc[r] - SHIFT);                                          \
      ps[g][r] += e_;                                                             \
      int q_  = 16 * g + lk * 4 + r;                                              \
      int byt = (q_ << 12) + ((kb_ + l15) << 1); byt ^= (q_ & 7) << 4;            \
      *(unsigned short*)(e_lds + byt) = f2bf(e_);                                 \
    } }                                                                           \
} while (0)

  // Phase A: 16 k-subtiles per wave, 4-deep register prefetch (3-step cover)
  KLOAD(kA, 0); KLOAD(kB, 1); KLOAD(kC, 2); KLOAD(kD, 3);
  ACOMP(kA, 0);  KLOAD(kA, 4);
  ACOMP(kB, 1);  KLOAD(kB, 5);
  ACOMP(kC, 2);  KLOAD(kC, 6);
  ACOMP(kD, 3);  KLOAD(kD, 7);
  ACOMP(kA, 4);  KLOAD(kA, 8);
  ACOMP(kB, 5);  KLOAD(kB, 9);
  ACOMP(kC, 6);  KLOAD(kC, 10);
  ACOMP(kD, 7);  KLOAD(kD, 11);
  ACOMP(kA, 8);  KLOAD(kA, 12);
  ACOMP(kB, 9);  KLOAD(kB, 13);
  ACOMP(kC, 10); KLOAD(kC, 14);
  ACOMP(kD, 11); KLOAD(kD, 15);
  ACOMP(kA, 12); ACOMP(kB, 13); ACOMP(kC, 14); ACOMP(kD, 15);
#undef KLOAD
#undef ACOMP

  // row-sum reduce (16 lanes share a q-row) + 8-wave combine
#pragma unroll
  for (int g = 0; g < 2; ++g)
#pragma unroll
    for (int r = 0; r < 4; ++r) {
      float v = ps[g][r];
      v += __shfl_xor(v, 1);
      v += __shfl_xor(v, 2);
      v += __shfl_xor(v, 4);
      v += __shfl_xor(v, 8);
      if (l15 == 0) red[w * 32 + 16 * g + lk * 4 + r] = v;
    }
  __syncthreads();
  if (tid < 32) {
    float s = 0.f;
#pragma unroll
    for (int i = 0; i < 8; ++i) s += red[i * 32 + tid];
    linv[tid] = 1.0f / s;
  }
  __syncthreads();

  // Phase B: O = (e @ V) * linv ; W rows streamed out interleaved.
  // 6-deep V prefetch (5-step cover).
  const int d0 = w << 4;
  const size_t vbase = (size_t)(d0 + l15) * SEQ + lk * 8;
  f32x4 acc2[2] = {{0.f,0.f,0.f,0.f},{0.f,0.f,0.f,0.f}};
  short8 v0, v1, v2, v3, v4, v5;

#define VLOAD(buf, stp) do { buf = *(const short8*)(Vtb + vbase + ((size_t)(stp) << 5)); } while (0)

#define VUSE(buf, stp) do {                                                      \
  int _kb2 = ((((stp) << 5) + lk * 8) << 1);                                     \
  _Pragma("unroll") for (int g = 0; g < 2; ++g) {                                \
    int _q  = 16 * g + l15;                                                      \
    int _by = (_q << 12) + _kb2; _by ^= (_q & 7) << 4;                           \
    short8 _af = *(const short8*)(e_lds + _by);                                  \
    acc2[g] = __builtin_amdgcn_mfma_f32_16x16x32_bf16(_af, buf, acc2[g], 0, 0, 0); \
  }                                                                              \
  if (((stp) & 1) == 0) {                                                        \
    int _r = (stp) >> 1; float _sc = linv[_r];                                   \
    int _b2 = (_r << 12) + (tid << 3); _b2 ^= (_r & 7) << 4;                     \
    uint2 _e4 = *(const uint2*)(e_lds + _b2);                                    \
    float4 _o; _o.x = bf2f(_e4.x & 0xffffu) * _sc; _o.y = bf2f(_e4.x >> 16) * _sc; \
    _o.z = bf2f(_e4.y & 0xffffu) * _sc; _o.w = bf2f(_e4.y >> 16) * _sc;          \
    *(float4*)(Wo + (size_t)_r * SEQ + (tid << 2)) = _o;                         \
  }                                                                              \
} while (0)

  VLOAD(v0, 0); VLOAD(v1, 1); VLOAD(v2, 2);
  VLOAD(v3, 3); VLOAD(v4, 4); VLOAD(v5, 5);
#pragma unroll
  for (int i = 0; i < 10; ++i) {
    const int s0 = 6 * i;
    VUSE(v0, s0);     if (s0 +  6 < 64) VLOAD(v0, s0 + 6);
    VUSE(v1, s0 + 1); if (s0 +  7 < 64) VLOAD(v1, s0 + 7);
    VUSE(v2, s0 + 2); if (s0 +  8 < 64) VLOAD(v2, s0 + 8);
    VUSE(v3, s0 + 3); if (s0 +  9 < 64) VLOAD(v3, s0 + 9);
    VUSE(v4, s0 + 4); if (s0 + 10 < 64) VLOAD(v4, s0 + 10);
    VUSE(v5, s0 + 5); if (s0 + 11 < 64) VLOAD(v5, s0 + 11);
  }
  VUSE(v0, 60); VUSE(v1, 61); VUSE(v2, 62); VUSE(v3, 63);
#undef VLOAD
#undef VUSE

  // O write
#pragma unroll
  for (int g = 0; g < 2; ++g)
#pragma unroll
    for (int r = 0; r < 4; ++r) {
      int q = 16 * g + lk * 4 + r;
      Oo[(size_t)q * DIM + d0 + l15] = acc2[g][r] * linv[q];
    }
}

// ---------------- fallback (round-1 kernel, no workspace needed) ----------------
extern "C" __global__ __launch_bounds__(512, 2)
void sdpa_fused(const float* __restrict__ Qg, const float* __restrict__ Kg,
                const float* __restrict__ Vg, float* __restrict__ Og) {
  extern __shared__ char lds[];
  char*  e_lds = lds;
  float* red   = (float*)(lds + 131072);
  float* linv  = (float*)(lds + 131072 + 1024);

  const int tid = threadIdx.x;
  const int w   = tid >> 6;
  const int l   = tid & 63;
  const int l15 = l & 15;
  const int lk  = l >> 4;

  const int b  = blockIdx.x & 7;
  const int q0 = (blockIdx.x >> 3) << 5;

  const float* Qb = Qg + ((size_t)b * SEQ + q0) * DIM;
  const float* Kb = Kg + (size_t)b * SEQ * DIM;
  const float* Vb = Vg + (size_t)b * SEQ * DIM;
  float* Oo = Og + ((size_t)b * SEQ + q0) * DIM;
  float* Wo = Og + (size_t)NB * SEQ * DIM + ((size_t)b * SEQ + q0) * SEQ;

  short8 qh[2][4], ql[2][4];
#pragma unroll
  for (int g = 0; g < 2; ++g) {
    const float* qrow = Qb + (16 * g + l15) * DIM + lk * 8;
#pragma unroll
    for (int t = 0; t < 4; ++t) {
      float4 a = *(const float4*)(qrow + 32 * t);
      float4 c = *(const float4*)(qrow + 32 * t + 4);
      float vv[8] = {a.x, a.y, a.z, a.w, c.x, c.y, c.z, c.w};
      short8 h, lo;
#pragma unroll
      for (int j = 0; j < 8; ++j) {
        unsigned short hb = f2bf(vv[j]);
        h[j]  = (short)hb;
        lo[j] = (short)f2bf(vv[j] - bf2f(hb));
      }
      qh[g][t] = h; ql[g][t] = lo;
    }
  }

  float ps[2][4] = {{0.f,0.f,0.f,0.f},{0.f,0.f,0.f,0.f}};
  for (int sub = 0; sub < 16; ++sub) {
    const int kb = (w << 8) + (sub << 4);
    const float* krow = Kb + (kb + l15) * DIM + lk * 8;
    short8 kh[4], kl[4];
#pragma unroll
    for (int t = 0; t < 4; ++t) {
      float4 a = *(const float4*)(krow + 32 * t);
      float4 c = *(const float4*)(krow + 32 * t + 4);
      float vv[8] = {a.x, a.y, a.z, a.w, c.x, c.y, c.z, c.w};
      short8 h, lo;
#pragma unroll
      for (int j = 0; j < 8; ++j) {
        unsigned short hb = f2bf(vv[j]);
        h[j]  = (short)hb;
        lo[j] = (short)f2bf(vv[j] - bf2f(hb));
      }
      kh[t] = h; kl[t] = lo;
    }
#pragma unroll
    for (int g = 0; g < 2; ++g) {
      f32x4 acc = {0.f, 0.f, 0.f, 0.f};
#pragma unroll
      for (int t = 0; t < 4; ++t) {
        acc = __builtin_amdgcn_mfma_f32_16x16x32_bf16(qh[g][t], kh[t], acc, 0, 0, 0);
        acc = __builtin_amdgcn_mfma_f32_16x16x32_bf16(ql[g][t], kh[t], acc, 0, 0, 0);
        acc = __builtin_amdgcn_mfma_f32_16x16x32_bf16(qh[g][t], kl[t], acc, 0, 0, 0);
      }
#pragma unroll
      for (int r = 0; r < 4; ++r) {
        float e = __expf(acc[r] - SHIFT);
        ps[g][r] += e;
        int q   = 16 * g + lk * 4 + r;
        int byt = (q << 12) + ((kb + l15) << 1);
        byt ^= (q & 7) << 4;
        *(unsigned short*)(e_lds + byt) = f2bf(e);
      }
    }
  }

#pragma unroll
  for (int g = 0; g < 2; ++g)
#pragma unroll
    for (int r = 0; r < 4; ++r) {
      float v = ps[g][r];
      v += __shfl_xor(v, 1);
      v += __shfl_xor(v, 2);
      v += __shfl_xor(v, 4);
      v += __shfl_xor(v, 8);
      if (l15 == 0) red[w * 32 + 16 * g + lk * 4 + r] = v;
    }
  __syncthreads();
  if (tid < 32) {
    float s = 0.f;
#pragma unroll
    for (int i = 0; i < 8; ++i) s += red[i * 32 + tid];
    linv[tid] = 1.0f / s;
  }
  __syncthreads();

  const int d0 = w << 4;
  const int vbase = lk * 8 * DIM + d0 + l15;
  f32x4 acc2[2] = {{0.f,0.f,0.f,0.f},{0.f,0.f,0.f,0.f}};
  float vA[8], vB[8], vC[8];

#define VLOAD(buf, stp) do { int _ko = (stp) * (32 * DIM) + vbase;               \
  _Pragma("unroll") for (int j = 0; j < 8; ++j) buf[j] = Vb[_ko + j * DIM]; } while (0)

#define VUSE(buf, stp) do {                                                      \
  short8 _bf; _Pragma("unroll") for (int j = 0; j < 8; ++j) _bf[j] = (short)f2bf(buf[j]); \
  int _kb2 = ((((stp) << 5) + lk * 8) << 1);                                     \
  _Pragma("unroll") for (int g = 0; g < 2; ++g) {                                \
    int _q  = 16 * g + l15;                                                      \
    int _by = (_q << 12) + _kb2; _by ^= (_q & 7) << 4;                           \
    short8 _af = *(const short8*)(e_lds + _by);                                  \
    acc2[g] = __builtin_amdgcn_mfma_f32_16x16x32_bf16(_af, _bf, acc2[g], 0, 0, 0); \
  }                                                                              \
  if (((stp) & 1) == 0) {                                                        \
    int _r = (stp) >> 1; float _sc = linv[_r];                                   \
    int _b2 = (_r << 12) + (tid << 3); _b2 ^= (_r & 7) << 4;                     \
    uint2 _e4 = *(const uint2*)(e_lds + _b2);                                    \
    float4 _o; _o.x = bf2f(_e4.x & 0xffffu) * _sc; _o.y = bf2f(_e4.x >> 16) * _sc; \
    _o.z = bf2f(_e4.y & 0xffffu) * _sc; _o.w = bf2f(_e4.y >> 16) * _sc;          \
    *(float4*)(Wo + (size_t)_r * SEQ + (tid << 2)) = _o;                         \
  }                                                                              \
} while (0)

  VLOAD(vA, 0); VLOAD(vB, 1);
  for (int i = 0; i < 21; ++i) {
    const int s0 = 3 * i;
    VLOAD(vC, s0 + 2);
    VUSE(vA, s0);
    if (s0 + 3 < 64) VLOAD(vA, s0 + 3);
    VUSE(vB, s0 + 1);
    if (s0 + 4 < 64) VLOAD(vB, s0 + 4);
    VUSE(vC, s0 + 2);
  }
  VUSE(vA, 63);
#undef VLOAD
#undef VUSE

#pragma unroll
  for (int g = 0; g < 2; ++g)
#pragma unroll
    for (int r = 0; r < 4; ++r) {
      int q = 16 * g + lk * 4 + r;
      Oo[(size_t)q * DIM + d0 + l15] = acc2[g][r] * linv[q];
    }
}

extern "C" void kernel_launch(void* const* d_in, const int* in_sizes, int n_in,
                              void* d_out, int out_size, void* d_ws, size_t ws_size,
                              hipStream_t stream) {
  const float* Q = (const float*)d_in[0];
  const float* K = (const float*)d_in[1];
  const float* V = (const float*)d_in[2];
  float* out = (float*)d_out;
  (void)in_sizes; (void)n_in; (void)out_size;

  const size_t need = (size_t)NELEM * 2u * 3u;   // Qf + Kf + Vt = 12,582,912 B
  if (ws_size >= need && d_ws != nullptr) {
    _Float16* Qf = (_Float16*)d_ws;
    _Float16* Kf = Qf + NELEM;
    unsigned short* Vt = (unsigned short*)(Kf + NELEM);
    prep_qk<<<dim3(2048), dim3(256), 0, stream>>>(Q, K, Qf, Kf);
    prep_v<<<dim3(512), dim3(256), 0, stream>>>(V, Vt);
    hipFuncSetAttribute((const void*)sdpa_main,
                        hipFuncAttributeMaxDynamicSharedMemorySize, 132224);
    sdpa_main<<<dim3(NB * (SEQ / 32)), dim3(512), 132224, stream>>>(Qf, Kf, Vt, out);
  } else {
    hipFuncSetAttribute((const void*)sdpa_fused,
                        hipFuncAttributeMaxDynamicSharedMemorySize, 132224);
    sdpa_fused<<<dim3(NB * (SEQ / 32)), dim3(512), 132224, stream>>>(Q, K, V, out);
  }
}